// Round 6
// baseline (347.779 us; speedup 1.0000x reference)
//
#include <hip/hip_runtime.h>

// Problem constants
#define BB 16
#define TT 64
#define HH 256
#define NSUB 16              // blocks per batch, all-to-all (1 RT/step)
#define ROWS 16              // rows of M per block = HH / NSUB
#define NBLK (BB * NSUB)     // 256 blocks

// d_out layout (floats): hid[B][T][H], out[B][T][2], h_fin[B][H], new_j[B][H][H]
#define OUT_OFF  (BB * TT * HH)            // 262144
#define HFIN_OFF (OUT_OFF + BB * TT * 2)   // 264192
#define NJ_OFF   (HFIN_OFF + BB * HH)      // 268288

// beta * SIGMA_SYN * sqrt(beta) = 0.1 * 0.002 * sqrt(0.1)
#define C_SN    6.324555320336759e-05f
// PERT_SIGMA * sqrt(ALPHA) = 0.1 * 0.5
#define C_NOISE 0.05f

typedef unsigned long long u64;
typedef unsigned int u32;

// Publish: exchange RMW -> executes at the device coherence point (proven r4/r5).
__device__ __forceinline__ void slot_put(u64* p, u64 v) {
    (void)__hip_atomic_exchange(p, v, __ATOMIC_RELAXED, __HIP_MEMORY_SCOPE_AGENT);
}
// Guaranteed-fresh read (RMW) -- fallback path only.
__device__ __forceinline__ u64 slot_get(u64* p) {
    return __hip_atomic_fetch_add(p, 0ull, __ATOMIC_RELAXED, __HIP_MEMORY_SCOPE_AGENT);
}
// Fast poll read: system-scope relaxed load -> sc0+sc1 (bypass L1/L2), regular
// load path (no atomic-unit serialization). Tag-protected: staleness can only
// delay, never corrupt.
__device__ __forceinline__ u64 slot_peek(u64* p) {
    return __hip_atomic_load(p, __ATOMIC_RELAXED, __HIP_MEMORY_SCOPE_SYSTEM);
}
__device__ __forceinline__ u64 pack(u32 tag, float v) {
    return ((u64)tag << 32) | (u64)__float_as_uint(v);
}

__global__ __launch_bounds__(256) void rnn_all(
    const float* __restrict__ x,      // [B,T,2]
    const float* __restrict__ h0,     // [B,H]
    const float* __restrict__ w_in,   // [H,2]
    const float* __restrict__ w_hh,   // [H,H]
    const float* __restrict__ b_hh,   // [H]
    const float* __restrict__ w_out,  // [2,H]
    const float* __restrict__ nper,   // [B,H]
    const float* __restrict__ sn,     // [T,B,H,H]
    const int*   __restrict__ pt_ptr, // scalar
    float*       __restrict__ dout,
    u32*         __restrict__ cnt_base) // d_ws: 16 counters, 256B stride
{
    const int tid = threadIdx.x;          // column j
    const int bid = blockIdx.x;
    const int b   = bid >> 4;             // batch
    const int sub = bid & (NSUB - 1);     // 0..15
    const int i0  = sub * ROWS;

    __shared__ float s_act[2][HH];
    __shared__ float s_red[8];
    __shared__ float s_x[2 * TT];

    u32* cnt = cnt_base + b * 64;         // 256B stride per batch

    // partial slots [2][NSUB][HH] u64 (64 KB) at the start of batch b's new_j
    // output region; memset to 0 each launch (tag 0 never matches).
    u64* slotbase = (u64*)(dout + NJ_OFF + (size_t)b * (HH * HH));

    const int pt = *pt_ptr;

    // M[i][j] = w_hh[j][i] + diff[i][j]; starts as transposed w_hh (diff = 0)
    float M[ROWS];
    {
        const float4* wr = (const float4*)(w_hh + (size_t)tid * HH + i0);
        #pragma unroll
        for (int q = 0; q < ROWS / 4; ++q) {
            float4 a = wr[q];
            M[4*q+0] = a.x; M[4*q+1] = a.y; M[4*q+2] = a.z; M[4*q+3] = a.w;
        }
    }

    float h    = h0[b * HH + tid];
    float actj = tanhf(h);
    s_act[0][tid] = actj;
    if (tid < 2 * TT) s_x[tid] = x[b * 2 * TT + tid];

    const float win0 = w_in[tid * 2 + 0];
    const float win1 = w_in[tid * 2 + 1];
    const float bh   = b_hh[tid];
    const float npv  = nper[b * HH + tid] * C_NOISE;
    const float wo0  = w_out[tid];
    const float wo1  = w_out[HH + tid];

    // prefetch sn[t=0] rows for this block
    float sreg[ROWS];
    {
        const float* snp = sn + ((size_t)b * HH + i0) * HH + tid;
        #pragma unroll
        for (int r = 0; r < ROWS; ++r) sreg[r] = snp[(size_t)r * HH];
    }
    __syncthreads();

    for (int t = 0; t < TT; ++t) {
        const int cur = t & 1, nxt = cur ^ 1;
        const u32 tagw = (u32)(t + 1);

        // ---- partial matvec with pre-update M (act of time t); publish ASAP
        float partial = 0.f;
        #pragma unroll
        for (int r = 0; r < ROWS; ++r) partial += s_act[cur][i0 + r] * M[r];

        slot_put(slotbase + (cur * NSUB + sub) * HH + tid, pack(tagw, partial));

        // ---- shadow work: M step-t update (outer + sn[t]), sn[t+1] prefetch
        #pragma unroll
        for (int r = 0; r < ROWS; ++r)
            M[r] += C_SN * sreg[r] - 0.1f * s_act[cur][i0 + r] * actj;

        if (t + 1 < TT) {
            const float* snp = sn + (((size_t)(t + 1) * BB + b) * HH + i0) * HH + tid;
            #pragma unroll
            for (int r = 0; r < ROWS; ++r) sreg[r] = snp[(size_t)r * HH];
        }

        // ---- all-to-all poll of the other 15 partials for column tid.
        // Phase 1: system-scope loads (full load BW). Phase 2 (insurance):
        // RMW reads, guaranteed fresh -> bounded staleness, no deadlock.
        float vv[NSUB];
        u32 mask = 0xFFFFu ^ (1u << sub);
        u64* sl = slotbase + cur * (NSUB * HH) + tid;
        int spins = 0;
        while (mask && spins < 64) {
            ++spins;
            #pragma unroll
            for (int s = 0; s < NSUB; ++s) {
                if (mask & (1u << s)) {
                    u64 v = slot_peek(sl + s * HH);
                    if ((u32)(v >> 32) == tagw) {
                        vv[s] = __uint_as_float((u32)v);
                        mask &= ~(1u << s);
                    }
                }
            }
        }
        while (mask) {
            #pragma unroll
            for (int s = 0; s < NSUB; ++s) {
                if (mask & (1u << s)) {
                    u64 v = slot_get(sl + s * HH);
                    if ((u32)(v >> 32) == tagw) {
                        vv[s] = __uint_as_float((u32)v);
                        mask &= ~(1u << s);
                    }
                }
            }
        }

        // ---- fixed s-order sum: bit-identical across blocks and replays
        float dj = 0.f;
        #pragma unroll
        for (int s = 0; s < NSUB; ++s) dj += (s == sub) ? partial : vv[s];

        // ---- h update (redundant per block; bitwise identical)
        const float tmp = s_x[2*t] * win0 + s_x[2*t+1] * win1 + bh + dj;
        h = 0.75f * h + 0.25f * tmp + ((t == pt) ? npv : 0.f);
        actj = tanhf(h);
        s_act[nxt][tid] = actj;

        // ---- outputs (split across sub-blocks)
        if (sub == 0) {
            dout[((size_t)b * TT + t) * HH + tid] = h;
        } else if (sub == 1) {
            float p0 = h * wo0, p1 = h * wo1;
            #pragma unroll
            for (int off = 32; off > 0; off >>= 1) {
                p0 += __shfl_down(p0, off, 64);
                p1 += __shfl_down(p1, off, 64);
            }
            const int wv = tid >> 6, ln = tid & 63;
            if (ln == 0) { s_red[wv] = p0; s_red[4 + wv] = p1; }
            __syncthreads();               // block-uniform branch: legal
            if (tid == 0) {
                dout[OUT_OFF + (b * TT + t) * 2 + 0] = s_red[0] + s_red[1] + s_red[2] + s_red[3];
                dout[OUT_OFF + (b * TT + t) * 2 + 1] = s_red[4] + s_red[5] + s_red[6] + s_red[7];
            }
        } else if (sub == 2 && t == TT - 1) {
            dout[HFIN_OFF + b * HH + tid] = h;
        }
        __syncthreads();                   // s_act[nxt] ready for next step
    }

    // ---- final per-batch arrival barrier (RMW counter): all blocks done
    // reading the packet slots before we overwrite the region with new_j.
    if (tid == 0) {
        (void)__hip_atomic_fetch_add(cnt, 1u, __ATOMIC_RELAXED, __HIP_MEMORY_SCOPE_AGENT);
        while (__hip_atomic_fetch_add(cnt, 0u, __ATOMIC_RELAXED, __HIP_MEMORY_SCOPE_AGENT)
               < (u32)NSUB)
            __builtin_amdgcn_s_sleep(2);
    }
    __syncthreads();

    // ---- write new_j[b][i][j] = w_hh[i][j] + (M[i][j] - w_hh[j][i])
    #pragma unroll
    for (int r = 0; r < ROWS; ++r) {
        const int i = i0 + r;
        dout[NJ_OFF + ((size_t)b * HH + i) * HH + tid] =
            w_hh[(size_t)i * HH + tid] + M[r] - w_hh[(size_t)tid * HH + i];
    }
}

extern "C" void kernel_launch(void* const* d_in, const int* in_sizes, int n_in,
                              void* d_out, int out_size, void* d_ws, size_t ws_size,
                              hipStream_t stream) {
    (void)in_sizes; (void)n_in; (void)out_size; (void)ws_size;
    const float* x     = (const float*)d_in[0];
    const float* h0    = (const float*)d_in[1];
    const float* w_in  = (const float*)d_in[2];
    const float* w_hh  = (const float*)d_in[3];
    const float* b_hh  = (const float*)d_in[4];
    const float* w_out = (const float*)d_in[5];
    const float* nper  = (const float*)d_in[6];
    const float* sn    = (const float*)d_in[7];
    const int*   pt    = (const int*)d_in[8];
    float* dout        = (float*)d_out;
    u32* cnt           = (u32*)d_ws;

    // reset barrier counters and the tagged-slot scratch (tags -> 0) each
    // launch so graph replays are deterministic (buffers are poisoned 0xAA).
    hipMemsetAsync(d_ws, 0, 16 * 64 * sizeof(u32), stream);
    hipMemsetAsync((void*)(dout + NJ_OFF), 0, (size_t)BB * HH * HH * sizeof(float), stream);

    rnn_all<<<dim3(NBLK), dim3(256), 0, stream>>>(
        x, h0, w_in, w_hh, b_hh, w_out, nper, sn, pt, dout, cnt);
}

// Round 7
// 143.015 us; speedup vs baseline: 2.4318x; 2.4318x over previous
//
#include <hip/hip_runtime.h>

// Problem constants
#define BB 16
#define TT 64
#define HH 256
#define NSUB 16              // blocks per batch; block owns a 16-COLUMN slice
#define NBLK (BB * NSUB)     // 256 blocks

// d_out layout (floats): hid[B][T][H], out[B][T][2], h_fin[B][H], new_j[B][H][H]
#define OUT_OFF  (BB * TT * HH)            // 262144
#define HFIN_OFF (OUT_OFF + BB * TT * 2)   // 264192
#define NJ_OFF   (HFIN_OFF + BB * HH)      // 268288

// beta * SIGMA_SYN * sqrt(beta) = 0.1 * 0.002 * sqrt(0.1)
#define C_SN    6.324555320336759e-05f
// PERT_SIGMA * sqrt(ALPHA) = 0.1 * 0.5
#define C_NOISE 0.05f

typedef unsigned long long u64;
typedef unsigned int u32;

// Agent-scope RMWs: execute at the device coherence point (proven r4/r5);
// exchange pushes data out, fetch_add(0) reads guaranteed-fresh. Tag travels
// with the data in one 8B packet -> no fences, no ordering assumptions.
// (r6 lesson: system-scope loads bypass MALL -> HBM flood. Never again.)
__device__ __forceinline__ void slot_put(u64* p, u64 v) {
    (void)__hip_atomic_exchange(p, v, __ATOMIC_RELAXED, __HIP_MEMORY_SCOPE_AGENT);
}
__device__ __forceinline__ u64 slot_get(u64* p) {
    return __hip_atomic_fetch_add(p, 0ull, __ATOMIC_RELAXED, __HIP_MEMORY_SCOPE_AGENT);
}
__device__ __forceinline__ u64 pack(u32 tag, float v) {
    return ((u64)tag << 32) | (u64)__float_as_uint(v);
}

__global__ __launch_bounds__(256) void rnn_all(
    const float* __restrict__ x,      // [B,T,2]
    const float* __restrict__ h0,     // [B,H]
    const float* __restrict__ w_in,   // [H,2]
    const float* __restrict__ w_hh,   // [H,H]
    const float* __restrict__ b_hh,   // [H]
    const float* __restrict__ w_out,  // [2,H]
    const float* __restrict__ nper,   // [B,H]
    const float* __restrict__ sn,     // [T,B,H,H]
    const int*   __restrict__ pt_ptr, // scalar
    float*       __restrict__ dout,
    u64*         __restrict__ ws)     // d_ws: [BB][2][NSUB][16] u64 slots
{
    const int tid = threadIdx.x;
    const int bid = blockIdx.x;
    const int b   = bid >> 4;             // batch
    const int sub = bid & 15;             // column-slice owner
    const int j0  = sub * 16;
    const int q     = tid & 15;           // col within slice
    const int rbase = tid >> 4;           // this thread's rows: i = rbase+16m
    const int jcol  = j0 + q;             // this thread's M column (global)
    const int wv = tid >> 6, ln = tid & 63;

    __shared__ float s_h[2][HH];
    __shared__ float s_act[HH];
    __shared__ float s_red[4][16];
    __shared__ float s_o[4][2];
    __shared__ float s_x[2 * TT];
    __shared__ float s_wt[16][HH];        // w_hh rows j0..j0+15 (transposed access)

    u64* slotb = ws + (size_t)b * (2 * NSUB * 16);

    const int pt = *pt_ptr;

    // ---- prologue: stage w_hh slice rows, h0, x
    for (int idx = tid; idx < 16 * HH; idx += 256)
        s_wt[idx >> 8][idx & 255] = w_hh[(size_t)(j0 + (idx >> 8)) * HH + (idx & 255)];
    s_h[0][tid] = h0[b * HH + tid];
    if (tid < 2 * TT) s_x[tid] = x[b * 2 * TT + tid];

    float win0 = 0.f, win1 = 0.f, bh = 0.f, npv = 0.f;
    if (tid < 16) {
        win0 = w_in[jcol * 2 + 0];
        win1 = w_in[jcol * 2 + 1];
        bh   = b_hh[jcol];
        npv  = nper[b * HH + jcol] * C_NOISE;
    }
    const float wo0 = w_out[tid], wo1 = w_out[HH + tid];
    __syncthreads();

    // M_loc[m] = M[i][jcol] with i = rbase+16m ; init = w_hh[jcol][i] (diff=0)
    float M_loc[16];
    #pragma unroll
    for (int m = 0; m < 16; ++m) M_loc[m] = s_wt[q][rbase + 16 * m];

    // sn prefetch t=0: sn[0][b][i][jcol]
    float sreg[16];
    {
        const float* snp = sn + ((size_t)b * HH + rbase) * HH + jcol;
        #pragma unroll
        for (int m = 0; m < 16; ++m) sreg[m] = snp[(size_t)(16 * m) * HH];
    }

    for (int t = 0; t < TT; ++t) {
        const int cur = t & 1, nxt = cur ^ 1;
        const u32 tagw = (u32)(t + 1);

        // act_t for all rows (each block computes tanh locally)
        s_act[tid] = tanhf(s_h[cur][tid]);
        __syncthreads();

        // ---- full dot for own columns: p = partial over rows rbase+16m
        float p = 0.f;
        #pragma unroll
        for (int m = 0; m < 16; ++m) p += s_act[rbase + 16 * m] * M_loc[m];
        p += __shfl_xor(p, 16, 64);       // combine rbase ^1
        p += __shfl_xor(p, 32, 64);       // combine rbase ^2
        if (ln < 16) s_red[wv][ln] = p;   // per-wave col sums (rows mod16 group)
        __syncthreads();

        // ---- h update for own 16 columns; publish immediately
        if (tid < 16) {
            const float dj  = s_red[0][q] + s_red[1][q] + s_red[2][q] + s_red[3][q];
            const float tmp = s_x[2 * t] * win0 + s_x[2 * t + 1] * win1 + bh + dj;
            const float hn  = 0.75f * s_h[cur][jcol] + 0.25f * tmp
                            + ((t == pt) ? npv : 0.f);
            s_h[nxt][jcol] = hn;
            dout[((size_t)b * TT + t) * HH + jcol] = hn;   // hid[b][t][jcol]
            slot_put(slotb + (cur * NSUB + sub) * 16 + q, pack(tagw, hn));
        }

        // ---- shadow: M step-t update (outer + sn[t]), prefetch sn[t+1]
        const float acol = s_act[jcol];
        #pragma unroll
        for (int m = 0; m < 16; ++m)
            M_loc[m] += C_SN * sreg[m] - 0.1f * s_act[rbase + 16 * m] * acol;
        if (t + 1 < TT) {
            const float* snp = sn + (((size_t)(t + 1) * BB + b) * HH + rbase) * HH + jcol;
            #pragma unroll
            for (int m = 0; m < 16; ++m) sreg[m] = snp[(size_t)(16 * m) * HH];
        }
        // sub1 shadow: out[b][t-1] = h_t @ w_out^T (h_t = s_h[cur], stable)
        if (sub == 1) {
            float p0 = s_h[cur][tid] * wo0, p1 = s_h[cur][tid] * wo1;
            #pragma unroll
            for (int off = 32; off; off >>= 1) {
                p0 += __shfl_down(p0, off, 64);
                p1 += __shfl_down(p1, off, 64);
            }
            if (ln == 0) { s_o[wv][0] = p0; s_o[wv][1] = p1; }
        }

        // ---- poll: ONE foreign slot per thread (240 pollers), tight RMW spin
        if (tid < 240) {
            int fs = tid >> 4; fs += (fs >= sub);          // foreign sub id
            u64* sp = slotb + (cur * NSUB + fs) * 16 + (tid & 15);
            u64 v;
            for (;;) {
                v = slot_get(sp);
                if ((u32)(v >> 32) == tagw) break;
                v = slot_get(sp);
                if ((u32)(v >> 32) == tagw) break;
            }
            s_h[nxt][fs * 16 + (tid & 15)] = __uint_as_float((u32)v);
        }
        __syncthreads();                   // s_h[nxt] complete

        if (sub == 1 && tid == 0 && t > 0) {
            dout[OUT_OFF + ((size_t)b * TT + (t - 1)) * 2 + 0] =
                s_o[0][0] + s_o[1][0] + s_o[2][0] + s_o[3][0];
            dout[OUT_OFF + ((size_t)b * TT + (t - 1)) * 2 + 1] =
                s_o[0][1] + s_o[1][1] + s_o[2][1] + s_o[3][1];
        }
    }

    // ---- epilogue: s_h[0] = h_64 (TT even)
    if (sub == 1) {
        float p0 = s_h[0][tid] * wo0, p1 = s_h[0][tid] * wo1;
        #pragma unroll
        for (int off = 32; off; off >>= 1) {
            p0 += __shfl_down(p0, off, 64);
            p1 += __shfl_down(p1, off, 64);
        }
        if (ln == 0) { s_o[wv][0] = p0; s_o[wv][1] = p1; }
        __syncthreads();                   // block-uniform branch: legal
        if (tid == 0) {
            dout[OUT_OFF + ((size_t)b * TT + (TT - 1)) * 2 + 0] =
                s_o[0][0] + s_o[1][0] + s_o[2][0] + s_o[3][0];
            dout[OUT_OFF + ((size_t)b * TT + (TT - 1)) * 2 + 1] =
                s_o[0][1] + s_o[1][1] + s_o[2][1] + s_o[3][1];
        }
    }
    if (sub == 2) dout[HFIN_OFF + b * HH + tid] = s_h[0][tid];

    // new_j[b][i][jcol] = w_hh[i][jcol] + (M_loc - w_hh[jcol][i])
    #pragma unroll
    for (int m = 0; m < 16; ++m) {
        const int i = rbase + 16 * m;
        dout[NJ_OFF + ((size_t)b * HH + i) * HH + jcol] =
            w_hh[(size_t)i * HH + jcol] + M_loc[m] - s_wt[q][i];
    }
}

extern "C" void kernel_launch(void* const* d_in, const int* in_sizes, int n_in,
                              void* d_out, int out_size, void* d_ws, size_t ws_size,
                              hipStream_t stream) {
    (void)in_sizes; (void)n_in; (void)out_size; (void)ws_size;
    const float* x     = (const float*)d_in[0];
    const float* h0    = (const float*)d_in[1];
    const float* w_in  = (const float*)d_in[2];
    const float* w_hh  = (const float*)d_in[3];
    const float* b_hh  = (const float*)d_in[4];
    const float* w_out = (const float*)d_in[5];
    const float* nper  = (const float*)d_in[6];
    const float* sn    = (const float*)d_in[7];
    const int*   pt    = (const int*)d_in[8];
    float* dout        = (float*)d_out;
    u64* ws            = (u64*)d_ws;

    // zero the tagged slots each launch (tag 0 never matches; buffers are
    // poisoned 0xAA once and NOT re-poisoned between graph replays).
    hipMemsetAsync(d_ws, 0, (size_t)BB * 2 * NSUB * 16 * sizeof(u64), stream);

    rnn_all<<<dim3(NBLK), dim3(256), 0, stream>>>(
        x, h0, w_in, w_hh, b_hh, w_out, nper, sn, pt, dout, ws);
}

// Round 9
// 142.824 us; speedup vs baseline: 2.4350x; 1.0013x over previous
//
#include <hip/hip_runtime.h>

// Problem constants
#define BB 16
#define TT 64
#define HH 256
#define NSUB 16              // blocks per batch; block owns a 16-COLUMN slice
#define NBLK (BB * NSUB)     // 256 blocks

// d_out layout (floats): hid[B][T][H], out[B][T][2], h_fin[B][H], new_j[B][H][H]
#define OUT_OFF  (BB * TT * HH)            // 262144
#define HFIN_OFF (OUT_OFF + BB * TT * 2)   // 264192
#define NJ_OFF   (HFIN_OFF + BB * HH)      // 268288

// beta * SIGMA_SYN * sqrt(beta) = 0.1 * 0.002 * sqrt(0.1)
#define C_SN    6.324555320336759e-05f
// PERT_SIGMA * sqrt(ALPHA) = 0.1 * 0.5
#define C_NOISE 0.05f

typedef unsigned long long u64;
typedef unsigned int u32;

// Agent-scope RMWs: execute at the device coherence point (proven r4/r5/r7);
// exchange pushes data out, fetch_add(0) reads guaranteed-fresh. Tag travels
// with the data in one 8B packet -> no fences, no ordering assumptions.
// (r6 lesson: system-scope relaxed loads bypass MALL -> HBM flood. r2 lesson:
// agent-scope relaxed loads can read stale XCD-L2 lines forever. RMW only.)
// (r8 lesson: the recurrence is chaotic -- sn must stay in it EXACTLY.)
__device__ __forceinline__ void slot_put(u64* p, u64 v) {
    (void)__hip_atomic_exchange(p, v, __ATOMIC_RELAXED, __HIP_MEMORY_SCOPE_AGENT);
}
__device__ __forceinline__ u64 slot_get(u64* p) {
    return __hip_atomic_fetch_add(p, 0ull, __ATOMIC_RELAXED, __HIP_MEMORY_SCOPE_AGENT);
}
__device__ __forceinline__ u64 pack(u32 tag, float v) {
    return ((u64)tag << 32) | (u64)__float_as_uint(v);
}

__global__ __launch_bounds__(256) void rnn_all(
    const float* __restrict__ x,      // [B,T,2]
    const float* __restrict__ h0,     // [B,H]
    const float* __restrict__ w_in,   // [H,2]
    const float* __restrict__ w_hh,   // [H,H]
    const float* __restrict__ b_hh,   // [H]
    const float* __restrict__ w_out,  // [2,H]
    const float* __restrict__ nper,   // [B,H]
    const float* __restrict__ sn,     // [T,B,H,H]
    const int*   __restrict__ pt_ptr, // scalar
    float*       __restrict__ dout,
    u64*         __restrict__ ws)     // d_ws: [BB][2][NSUB][16] u64 slots
{
    const int tid = threadIdx.x;
    const int bid = blockIdx.x;
    const int b   = bid >> 4;             // batch
    const int sub = bid & 15;             // column-slice owner
    const int j0  = sub * 16;
    const int q     = tid & 15;           // col within slice
    const int rbase = tid >> 4;           // this thread's rows: i = rbase+16m
    const int jcol  = j0 + q;             // this thread's M column (global)
    const int wv = tid >> 6, ln = tid & 63;

    // s_actT: TRANSPOSED act store: act[i] lives at [(i&15)*16 + (i>>4)]
    // -> thread (rbase,*) reads its 16 operands {rbase+16m} as 4 float4s.
    __shared__ float s_actT[2][HH];
    __shared__ float s_h[2][HH];          // raw h (for out / h_fin shadows)
    __shared__ float s_red[4][16];
    __shared__ float s_o[4][2];
    __shared__ float s_x[2 * TT];
    __shared__ float s_wt[16][HH];        // w_hh rows j0..j0+15

    u64* slotb = ws + (size_t)b * (2 * NSUB * 16);
    const int pt = *pt_ptr;

    // ---- prologue
    for (int idx = tid; idx < 16 * HH; idx += 256)
        s_wt[idx >> 8][idx & 255] = w_hh[(size_t)(j0 + (idx >> 8)) * HH + (idx & 255)];
    {
        const float hv = h0[b * HH + tid];
        s_h[0][tid] = hv;
        s_actT[0][(tid & 15) * 16 + (tid >> 4)] = tanhf(hv);
    }
    if (tid < 2 * TT) s_x[tid] = x[b * 2 * TT + tid];

    float wi0 = 0.f, wi1 = 0.f, bh = 0.f, npv = 0.f, hreg = 0.f;
    if (tid < 16) {
        wi0  = w_in[jcol * 2 + 0];
        wi1  = w_in[jcol * 2 + 1];
        bh   = b_hh[jcol];
        npv  = nper[b * HH + jcol] * C_NOISE;
        hreg = h0[b * HH + jcol];
    }
    const float wo0 = w_out[tid], wo1 = w_out[HH + tid];
    __syncthreads();

    // M[m] = M[i][jcol], i = rbase+16m ; init = w_hh[jcol][i] (diff = 0)
    float M[16];
    #pragma unroll
    for (int m = 0; m < 16; ++m) M[m] = s_wt[q][rbase + 16 * m];

    // sn prefetch t=0: sn[0][b][i][jcol]
    float sreg[16];
    {
        const float* snp = sn + ((size_t)b * HH + rbase) * HH + jcol;
        #pragma unroll
        for (int m = 0; m < 16; ++m) sreg[m] = snp[(size_t)(16 * m) * HH];
    }

    for (int t = 0; t < TT; ++t) {
        const int cur = t & 1, nxt = cur ^ 1;
        const u32 tagw = (u32)(t + 1);

        // ---- dot: act operands contiguous in s_actT -> 4 ds_read_b128
        float a[16];
        #pragma unroll
        for (int mq = 0; mq < 4; ++mq) {
            float4 v = *(const float4*)&s_actT[cur][rbase * 16 + mq * 4];
            a[mq * 4 + 0] = v.x; a[mq * 4 + 1] = v.y;
            a[mq * 4 + 2] = v.z; a[mq * 4 + 3] = v.w;
        }
        float p = 0.f;
        #pragma unroll
        for (int m = 0; m < 16; ++m) p += a[m] * M[m];
        p += __shfl_xor(p, 16, 64);       // combine rbase ^1
        p += __shfl_xor(p, 32, 64);       // combine rbase ^2
        if (ln < 16) s_red[wv][ln] = p;   // 4 wave-partials per column
        __syncthreads();                  // SYNC1

        // ---- owner: h update for own 16 columns, publish IMMEDIATELY
        if (tid < 16) {
            const float dj = s_red[0][tid] + s_red[1][tid]
                           + s_red[2][tid] + s_red[3][tid];
            const float tmp = s_x[2 * t] * wi0 + s_x[2 * t + 1] * wi1 + bh + dj;
            hreg = 0.75f * hreg + 0.25f * tmp + ((t == pt) ? npv : 0.f);
            slot_put(slotb + (cur * NSUB + sub) * 16 + tid, pack(tagw, hreg));
            s_h[nxt][jcol] = hreg;
            s_actT[nxt][q * 16 + sub] = tanhf(hreg);
            dout[((size_t)b * TT + t) * HH + jcol] = hreg;   // hid
        }

        // ---- shadow: M step-t update (outer + sn[t]), prefetch sn[t+1]
        const float aj = s_actT[cur][q * 16 + sub];          // act[jcol]
        #pragma unroll
        for (int m = 0; m < 16; ++m)
            M[m] += C_SN * sreg[m] - 0.1f * a[m] * aj;
        if (t + 1 < TT) {
            const float* snp = sn + (((size_t)(t + 1) * BB + b) * HH + rbase) * HH + jcol;
            #pragma unroll
            for (int m = 0; m < 16; ++m) sreg[m] = snp[(size_t)(16 * m) * HH];
        }
        // sub1 shadow: out[b][t-1] = h_t @ w_out^T  (h_t = s_h[cur], stable)
        if (sub == 1) {
            const float hv = s_h[cur][tid];
            float p0 = hv * wo0, p1 = hv * wo1;
            #pragma unroll
            for (int off = 32; off; off >>= 1) {
                p0 += __shfl_down(p0, off, 64);
                p1 += __shfl_down(p1, off, 64);
            }
            if (ln == 0) { s_o[wv][0] = p0; s_o[wv][1] = p1; }
        }

        // ---- poll: ONE foreign slot per thread, 4-deep pipelined RMW spin
        if (tid < 240) {
            int fs = tid >> 4; fs += (fs >= sub);            // foreign sub id
            const int fq = tid & 15;
            u64* sp = slotb + (cur * NSUB + fs) * 16 + fq;
            u64 v;
            u64 a0 = slot_get(sp), a1 = slot_get(sp),
                a2 = slot_get(sp), a3 = slot_get(sp);
            for (;;) {
                if ((u32)(a0 >> 32) == tagw) { v = a0; break; } a0 = slot_get(sp);
                if ((u32)(a1 >> 32) == tagw) { v = a1; break; } a1 = slot_get(sp);
                if ((u32)(a2 >> 32) == tagw) { v = a2; break; } a2 = slot_get(sp);
                if ((u32)(a3 >> 32) == tagw) { v = a3; break; } a3 = slot_get(sp);
            }
            const float hr = __uint_as_float((u32)v);
            s_h[nxt][fs * 16 + fq] = hr;
            s_actT[nxt][fq * 16 + fs] = tanhf(hr);           // fused tanh
        }
        __syncthreads();                  // SYNC2: s_h/s_actT[nxt] complete

        if (sub == 1 && tid == 0 && t > 0) {
            dout[OUT_OFF + ((size_t)b * TT + (t - 1)) * 2 + 0] =
                s_o[0][0] + s_o[1][0] + s_o[2][0] + s_o[3][0];
            dout[OUT_OFF + ((size_t)b * TT + (t - 1)) * 2 + 1] =
                s_o[0][1] + s_o[1][1] + s_o[2][1] + s_o[3][1];
        }
    }

    // ---- epilogue: s_h[0] = h_64 (TT even)
    if (sub == 1) {
        const float hv = s_h[0][tid];
        float p0 = hv * wo0, p1 = hv * wo1;
        #pragma unroll
        for (int off = 32; off; off >>= 1) {
            p0 += __shfl_down(p0, off, 64);
            p1 += __shfl_down(p1, off, 64);
        }
        if (ln == 0) { s_o[wv][0] = p0; s_o[wv][1] = p1; }
        __syncthreads();                   // block-uniform branch: legal
        if (tid == 0) {
            dout[OUT_OFF + ((size_t)b * TT + (TT - 1)) * 2 + 0] =
                s_o[0][0] + s_o[1][0] + s_o[2][0] + s_o[3][0];
            dout[OUT_OFF + ((size_t)b * TT + (TT - 1)) * 2 + 1] =
                s_o[0][1] + s_o[1][1] + s_o[2][1] + s_o[3][1];
        }
    }
    if (sub == 2) dout[HFIN_OFF + b * HH + tid] = s_h[0][tid];

    // new_j[b][i][jcol] = w_hh[i][jcol] + (M - w_hh[jcol][i])
    #pragma unroll
    for (int m = 0; m < 16; ++m) {
        const int i = rbase + 16 * m;
        dout[NJ_OFF + ((size_t)b * HH + i) * HH + jcol] =
            w_hh[(size_t)i * HH + jcol] + M[m] - s_wt[q][i];
    }
}

extern "C" void kernel_launch(void* const* d_in, const int* in_sizes, int n_in,
                              void* d_out, int out_size, void* d_ws, size_t ws_size,
                              hipStream_t stream) {
    (void)in_sizes; (void)n_in; (void)out_size; (void)ws_size;
    const float* x     = (const float*)d_in[0];
    const float* h0    = (const float*)d_in[1];
    const float* w_in  = (const float*)d_in[2];
    const float* w_hh  = (const float*)d_in[3];
    const float* b_hh  = (const float*)d_in[4];
    const float* w_out = (const float*)d_in[5];
    const float* nper  = (const float*)d_in[6];
    const float* sn    = (const float*)d_in[7];
    const int*   pt    = (const int*)d_in[8];
    float* dout        = (float*)d_out;
    u64* ws            = (u64*)d_ws;

    // zero the tagged slots each launch: tags are in [1,64], so a replayed
    // graph would otherwise see last launch's tags as valid.
    hipMemsetAsync(d_ws, 0, (size_t)BB * 2 * NSUB * 16 * sizeof(u64), stream);

    rnn_all<<<dim3(NBLK), dim3(256), 0, stream>>>(
        x, h0, w_in, w_hh, b_hh, w_out, nper, sn, pt, dout, ws);
}

// Round 11
// 135.614 us; speedup vs baseline: 2.5645x; 1.0532x over previous
//
#include <hip/hip_runtime.h>

// Problem constants
#define BB 16
#define TT 64
#define HH 256
#define NSUB 16              // blocks per batch; block owns a 16-COLUMN slice
#define NBLK (BB * NSUB)     // 256 blocks

// d_out layout (floats): hid[B][T][H], out[B][T][2], h_fin[B][H], new_j[B][H][H]
#define OUT_OFF  (BB * TT * HH)            // 262144
#define HFIN_OFF (OUT_OFF + BB * TT * 2)   // 264192
#define NJ_OFF   (HFIN_OFF + BB * HH)      // 268288

// beta * SIGMA_SYN * sqrt(beta) = 0.1 * 0.002 * sqrt(0.1)
#define C_SN    6.324555320336759e-05f
// PERT_SIGMA * sqrt(ALPHA) = 0.1 * 0.5
#define C_NOISE 0.05f

typedef unsigned long long u64;
typedef unsigned int u32;

// Agent-scope RMWs ONLY: execute at the device coherence point (proven
// r4/r5/r7/r9). Tag travels WITH the data in one 8B packet -> no fences.
// Lessons: r2 = relaxed agent loads go stale; r6 = system-scope loads flood
// HBM; r10 = mixed load-poll + barrier-free publish hangs; r8 = recurrence
// is chaotic, sn must stay exact. r9 vs r7 = deeper poll pipelines are
// SLOWER (atomic-unit queueing) -> this round throttles the poll instead.
__device__ __forceinline__ void slot_put(u64* p, u64 v) {
    (void)__hip_atomic_exchange(p, v, __ATOMIC_RELAXED, __HIP_MEMORY_SCOPE_AGENT);
}
__device__ __forceinline__ u64 slot_get(u64* p) {
    return __hip_atomic_fetch_add(p, 0ull, __ATOMIC_RELAXED, __HIP_MEMORY_SCOPE_AGENT);
}
__device__ __forceinline__ u64 pack(u32 tag, float v) {
    return ((u64)tag << 32) | (u64)__float_as_uint(v);
}

__global__ __launch_bounds__(256) void rnn_all(
    const float* __restrict__ x,      // [B,T,2]
    const float* __restrict__ h0,     // [B,H]
    const float* __restrict__ w_in,   // [H,2]
    const float* __restrict__ w_hh,   // [H,H]
    const float* __restrict__ b_hh,   // [H]
    const float* __restrict__ w_out,  // [2,H]
    const float* __restrict__ nper,   // [B,H]
    const float* __restrict__ sn,     // [T,B,H,H]
    const int*   __restrict__ pt_ptr, // scalar
    float*       __restrict__ dout,
    u64*         __restrict__ ws)     // d_ws: [BB][2][NSUB][16] u64 slots
{
    const int tid = threadIdx.x;
    const int bid = blockIdx.x;
    const int b   = bid >> 4;             // batch
    const int sub = bid & 15;             // column-slice owner
    const int j0  = sub * 16;
    const int q     = tid & 15;           // col within slice
    const int rbase = tid >> 4;           // this thread's rows: i = rbase+16m
    const int jcol  = j0 + q;             // this thread's M column (global)
    const int wv = tid >> 6, ln = tid & 63;

    // s_actT: TRANSPOSED act store: act[i] lives at [(i&15)*16 + (i>>4)]
    // -> thread (rbase,*) reads its 16 operands {rbase+16m} as 4 float4s.
    __shared__ float s_actT[2][HH];
    __shared__ float s_h[2][HH];          // raw h (for out / h_fin shadows)
    __shared__ float s_red[4][16];
    __shared__ float s_o[4][2];
    __shared__ float s_x[2 * TT];
    __shared__ float s_wt[16][HH];        // w_hh rows j0..j0+15

    u64* slotb = ws + (size_t)b * (2 * NSUB * 16);
    const int pt = *pt_ptr;

    // ---- prologue
    for (int idx = tid; idx < 16 * HH; idx += 256)
        s_wt[idx >> 8][idx & 255] = w_hh[(size_t)(j0 + (idx >> 8)) * HH + (idx & 255)];
    {
        const float hv = h0[b * HH + tid];
        s_h[0][tid] = hv;
        s_actT[0][(tid & 15) * 16 + (tid >> 4)] = tanhf(hv);
    }
    if (tid < 2 * TT) s_x[tid] = x[b * 2 * TT + tid];

    float wi0 = 0.f, wi1 = 0.f, bh = 0.f, npv = 0.f, hreg = 0.f;
    if (tid < 16) {
        wi0  = w_in[jcol * 2 + 0];
        wi1  = w_in[jcol * 2 + 1];
        bh   = b_hh[jcol];
        npv  = nper[b * HH + jcol] * C_NOISE;
        hreg = h0[b * HH + jcol];
    }
    const float wo0 = w_out[tid], wo1 = w_out[HH + tid];
    __syncthreads();

    // M[m] = M[i][jcol], i = rbase+16m ; init = w_hh[jcol][i] (diff = 0)
    float M[16];
    #pragma unroll
    for (int m = 0; m < 16; ++m) M[m] = s_wt[q][rbase + 16 * m];

    // sn prefetch t=0: sn[0][b][i][jcol]
    float sreg[16];
    {
        const float* snp = sn + ((size_t)b * HH + rbase) * HH + jcol;
        #pragma unroll
        for (int m = 0; m < 16; ++m) sreg[m] = snp[(size_t)(16 * m) * HH];
    }

    for (int t = 0; t < TT; ++t) {
        const int cur = t & 1, nxt = cur ^ 1;
        const u32 tagw = (u32)(t + 1);

        // ---- dot: act operands contiguous in s_actT -> 4 ds_read_b128
        float a[16];
        #pragma unroll
        for (int mq = 0; mq < 4; ++mq) {
            float4 v = *(const float4*)&s_actT[cur][rbase * 16 + mq * 4];
            a[mq * 4 + 0] = v.x; a[mq * 4 + 1] = v.y;
            a[mq * 4 + 2] = v.z; a[mq * 4 + 3] = v.w;
        }
        float p = 0.f;
        #pragma unroll
        for (int m = 0; m < 16; ++m) p += a[m] * M[m];
        p += __shfl_xor(p, 16, 64);       // combine rbase ^1
        p += __shfl_xor(p, 32, 64);       // combine rbase ^2
        if (ln < 16) s_red[wv][ln] = p;   // 4 wave-partials per column
        __syncthreads();                  // SYNC1

        // ---- owner: h update for own 16 columns, publish IMMEDIATELY
        if (tid < 16) {
            const float dj = s_red[0][tid] + s_red[1][tid]
                           + s_red[2][tid] + s_red[3][tid];
            const float tmp = s_x[2 * t] * wi0 + s_x[2 * t + 1] * wi1 + bh + dj;
            hreg = 0.75f * hreg + 0.25f * tmp + ((t == pt) ? npv : 0.f);
            slot_put(slotb + (cur * NSUB + sub) * 16 + tid, pack(tagw, hreg));
            s_h[nxt][jcol] = hreg;
            s_actT[nxt][q * 16 + sub] = tanhf(hreg);
            dout[((size_t)b * TT + t) * HH + jcol] = hreg;   // hid
        }

        // ---- shadow: M step-t update (outer + sn[t]), prefetch sn[t+1]
        const float aj = s_actT[cur][q * 16 + sub];          // act[jcol]
        #pragma unroll
        for (int m = 0; m < 16; ++m)
            M[m] += C_SN * sreg[m] - 0.1f * a[m] * aj;
        if (t + 1 < TT) {
            const float* snp = sn + (((size_t)(t + 1) * BB + b) * HH + rbase) * HH + jcol;
            #pragma unroll
            for (int m = 0; m < 16; ++m) sreg[m] = snp[(size_t)(16 * m) * HH];
        }
        // sub1 shadow: out[b][t-1] = h_t @ w_out^T  (h_t = s_h[cur], stable)
        if (sub == 1) {
            const float hv = s_h[cur][tid];
            float p0 = hv * wo0, p1 = hv * wo1;
            #pragma unroll
            for (int off = 32; off; off >>= 1) {
                p0 += __shfl_down(p0, off, 64);
                p1 += __shfl_down(p1, off, 64);
            }
            if (ln == 0) { s_o[wv][0] = p0; s_o[wv][1] = p1; }
        }

        // ---- poll: ONE foreign slot per thread, THROTTLED single-RMW spin.
        // s_sleep(1) (~64cy) between attempts cuts per-address RMW queueing
        // ~5-10x so the publisher's exchange lands in a near-empty queue.
        if (tid < 240) {
            int fs = tid >> 4; fs += (fs >= sub);            // foreign sub id
            const int fq = tid & 15;
            u64* sp = slotb + (cur * NSUB + fs) * 16 + fq;
            u64 v = slot_get(sp);
            while ((u32)(v >> 32) != tagw) {
                __builtin_amdgcn_s_sleep(1);
                v = slot_get(sp);
            }
            const float hr = __uint_as_float((u32)v);
            s_h[nxt][fs * 16 + fq] = hr;
            s_actT[nxt][fq * 16 + fs] = tanhf(hr);           // fused tanh
        }
        __syncthreads();                  // SYNC2: s_h/s_actT[nxt] complete

        if (sub == 1 && tid == 0 && t > 0) {
            dout[OUT_OFF + ((size_t)b * TT + (t - 1)) * 2 + 0] =
                s_o[0][0] + s_o[1][0] + s_o[2][0] + s_o[3][0];
            dout[OUT_OFF + ((size_t)b * TT + (t - 1)) * 2 + 1] =
                s_o[0][1] + s_o[1][1] + s_o[2][1] + s_o[3][1];
        }
    }

    // ---- epilogue: s_h[0] = h_64 (TT even)
    if (sub == 1) {
        const float hv = s_h[0][tid];
        float p0 = hv * wo0, p1 = hv * wo1;
        #pragma unroll
        for (int off = 32; off; off >>= 1) {
            p0 += __shfl_down(p0, off, 64);
            p1 += __shfl_down(p1, off, 64);
        }
        if (ln == 0) { s_o[wv][0] = p0; s_o[wv][1] = p1; }
        __syncthreads();                   // block-uniform branch: legal
        if (tid == 0) {
            dout[OUT_OFF + ((size_t)b * TT + (TT - 1)) * 2 + 0] =
                s_o[0][0] + s_o[1][0] + s_o[2][0] + s_o[3][0];
            dout[OUT_OFF + ((size_t)b * TT + (TT - 1)) * 2 + 1] =
                s_o[0][1] + s_o[1][1] + s_o[2][1] + s_o[3][1];
        }
    }
    if (sub == 2) dout[HFIN_OFF + b * HH + tid] = s_h[0][tid];

    // new_j[b][i][jcol] = w_hh[i][jcol] + (M - w_hh[jcol][i])
    #pragma unroll
    for (int m = 0; m < 16; ++m) {
        const int i = rbase + 16 * m;
        dout[NJ_OFF + ((size_t)b * HH + i) * HH + jcol] =
            w_hh[(size_t)i * HH + jcol] + M[m] - s_wt[q][i];
    }
}

extern "C" void kernel_launch(void* const* d_in, const int* in_sizes, int n_in,
                              void* d_out, int out_size, void* d_ws, size_t ws_size,
                              hipStream_t stream) {
    (void)in_sizes; (void)n_in; (void)out_size; (void)ws_size;
    const float* x     = (const float*)d_in[0];
    const float* h0    = (const float*)d_in[1];
    const float* w_in  = (const float*)d_in[2];
    const float* w_hh  = (const float*)d_in[3];
    const float* b_hh  = (const float*)d_in[4];
    const float* w_out = (const float*)d_in[5];
    const float* nper  = (const float*)d_in[6];
    const float* sn    = (const float*)d_in[7];
    const int*   pt    = (const int*)d_in[8];
    float* dout        = (float*)d_out;
    u64* ws            = (u64*)d_ws;

    // zero the tagged slots each launch: tags are in [1,64], so a replayed
    // graph would otherwise see last launch's tags as valid.
    hipMemsetAsync(d_ws, 0, (size_t)BB * 2 * NSUB * 16 * sizeof(u64), stream);

    rnn_all<<<dim3(NBLK), dim3(256), 0, stream>>>(
        x, h0, w_in, w_hh, b_hh, w_out, nper, sn, pt, dout, ws);
}